// Round 1
// baseline (3508.034 us; speedup 1.0000x reference)
//
#include <hip/hip_runtime.h>
#include <math.h>

#define TILE_BM 64
#define TILE_BK 16
#define H_DIM 1024
#define HH_DIM 512

// ---------------- W1 [512][1024] -> W1T [1024][512] ----------------
__global__ void transpose_w1_kernel(const float* __restrict__ W1,
                                    float* __restrict__ W1T,
                                    int Hh, int H) {
    __shared__ float tile[32][33];
    const int bx = blockIdx.x;  // along H (k)
    const int by = blockIdx.y;  // along Hh (n)
    const int tx = threadIdx.x; // 0..31
    const int ty = threadIdx.y; // 0..7
#pragma unroll
    for (int i = 0; i < 4; ++i) {
        int n = by * 32 + ty + i * 8;
        int k = bx * 32 + tx;
        tile[ty + i * 8][tx] = W1[(size_t)n * H + k];
    }
    __syncthreads();
#pragma unroll
    for (int i = 0; i < 4; ++i) {
        int k = bx * 32 + ty + i * 8;
        int n = by * 32 + tx;
        W1T[(size_t)k * Hh + n] = tile[tx][ty + i * 8];
    }
}

// ------- fused scorer: s_pre[b,n] = gelu(x@W1^T + b1) @ W2^T (monotonic-
// equivalent to reference's normalized sigmoid scores for selection) -------
__global__ __launch_bounds__(256, 2)
void score_kernel(const float* __restrict__ X, const float* __restrict__ W1T,
                  const float* __restrict__ b1, const float* __restrict__ W2,
                  float* __restrict__ scores) {
    __shared__ float As[TILE_BK][TILE_BM];   // 4 KB, A transposed: As[k][m]
    __shared__ float Bs[TILE_BK][HH_DIM];    // 32 KB, Bs[k][n]
    __shared__ float red[TILE_BM][33];       // 8.25 KB reduction pad

    const int t  = threadIdx.x;
    const int tc = t & 31;   // col group 0..31 (16 cols each, interleaved)
    const int tr = t >> 5;   // row group 0..7  (8 rows each)
    const size_t m0 = (size_t)blockIdx.x * TILE_BM;

    float acc[8][16];
#pragma unroll
    for (int i = 0; i < 8; ++i)
#pragma unroll
        for (int j = 0; j < 16; ++j) acc[i][j] = 0.f;

    const float* xbase = X + m0 * H_DIM;
    const int arow = t >> 2;        // 0..63
    const int ac4  = (t & 3) << 2;  // 0,4,8,12

    for (int k0 = 0; k0 < H_DIM; k0 += TILE_BK) {
        // prefetch next tiles into registers before the barrier
        float4 av = *(const float4*)(xbase + (size_t)arow * H_DIM + k0 + ac4);
        const float* bsrc = W1T + (size_t)k0 * HH_DIM;
        float4 bv[8];
#pragma unroll
        for (int r = 0; r < 8; ++r) {
            int idx = r * 256 + t;
            bv[r] = *(const float4*)(bsrc + (size_t)(idx >> 7) * HH_DIM + ((idx & 127) << 2));
        }
        __syncthreads();  // previous iteration's reads complete
        As[ac4 + 0][arow] = av.x;
        As[ac4 + 1][arow] = av.y;
        As[ac4 + 2][arow] = av.z;
        As[ac4 + 3][arow] = av.w;
#pragma unroll
        for (int r = 0; r < 8; ++r) {
            int idx = r * 256 + t;
            *(float4*)&Bs[idx >> 7][(idx & 127) << 2] = bv[r];
        }
        __syncthreads();
#pragma unroll
        for (int kk = 0; kk < TILE_BK; ++kk) {
            float4 a0 = *(const float4*)&As[kk][tr * 8];      // broadcast reads
            float4 a1 = *(const float4*)&As[kk][tr * 8 + 4];
            float a[8] = {a0.x, a0.y, a0.z, a0.w, a1.x, a1.y, a1.z, a1.w};
            float4 bb[4];
#pragma unroll
            for (int j = 0; j < 4; ++j)                        // stride-16B: conflict-free
                bb[j] = *(const float4*)&Bs[kk][tc * 4 + j * 128];
#pragma unroll
            for (int i = 0; i < 8; ++i) {
#pragma unroll
                for (int j = 0; j < 4; ++j) {
                    acc[i][j * 4 + 0] = fmaf(a[i], bb[j].x, acc[i][j * 4 + 0]);
                    acc[i][j * 4 + 1] = fmaf(a[i], bb[j].y, acc[i][j * 4 + 1]);
                    acc[i][j * 4 + 2] = fmaf(a[i], bb[j].z, acc[i][j * 4 + 2]);
                    acc[i][j * 4 + 3] = fmaf(a[i], bb[j].w, acc[i][j * 4 + 3]);
                }
            }
        }
    }

    // epilogue: + b1, exact gelu, dot with W2, reduce over 512 cols
    float part[8];
#pragma unroll
    for (int i = 0; i < 8; ++i) part[i] = 0.f;
#pragma unroll
    for (int j = 0; j < 4; ++j) {
        int nb = tc * 4 + j * 128;
        float4 b1v = *(const float4*)(b1 + nb);
        float4 w2v = *(const float4*)(W2 + nb);
        const float bsv[4] = {b1v.x, b1v.y, b1v.z, b1v.w};
        const float wsv[4] = {w2v.x, w2v.y, w2v.z, w2v.w};
#pragma unroll
        for (int jj = 0; jj < 4; ++jj) {
#pragma unroll
            for (int i = 0; i < 8; ++i) {
                float h = acc[i][j * 4 + jj] + bsv[jj];
                float g = 0.5f * h * (1.f + erff(h * 0.70710678118654752f));
                part[i] = fmaf(g, wsv[jj], part[i]);
            }
        }
    }
#pragma unroll
    for (int i = 0; i < 8; ++i) red[tr * 8 + i][tc] = part[i];
    __syncthreads();
    if (t < TILE_BM) {
        float s = 0.f;
#pragma unroll
        for (int c = 0; c < 32; ++c) s += red[t][c];
        scores[m0 + t] = s;  // pre-sigmoid, pre-normalization: same ordering
    }
}

// ------- per-segment top-quota selection (tie -> lower index, matching
// jax.lax.top_k) + ascending-index gather of the selected rows -------
__global__ void select_gather_kernel(const float* __restrict__ X,
                                     const float* __restrict__ scores,
                                     float* __restrict__ out,
                                     int N, int seg_len, int quota, int n_seg) {
    const int seg = blockIdx.x;
    const int b   = blockIdx.y;
    __shared__ float sc[64];
    __shared__ int sel_idx[64];
    const int t = threadIdx.x;
    if (t < seg_len) sc[t] = scores[(size_t)b * N + (size_t)seg * seg_len + t];
    __syncthreads();
    if (t == 0) {
        unsigned long long mask = 0ull;
        for (int it = 0; it < quota; ++it) {
            float best = 0.f;
            int bi = 0;
            bool found = false;
            for (int i = 0; i < seg_len; ++i) {
                if (!((mask >> i) & 1ull)) {
                    if (!found || sc[i] > best) { best = sc[i]; bi = i; found = true; }
                }
            }
            mask |= (1ull << bi);
        }
        int c = 0;
        for (int i = 0; i < seg_len; ++i)
            if ((mask >> i) & 1ull) sel_idx[c++] = i;  // ascending == sorted output
    }
    __syncthreads();
    const size_t HV = H_DIM / 4;
    const float4* xb = (const float4*)X + ((size_t)b * N + (size_t)seg * seg_len) * HV;
    float4* ob = (float4*)out + ((size_t)b * n_seg * quota + (size_t)seg * quota) * HV;
    for (int j = 0; j < quota; ++j) {
        const float4* srow = xb + (size_t)sel_idx[j] * HV;
        float4* drow = ob + (size_t)j * HV;
        for (int c = t; c < (int)HV; c += blockDim.x) drow[c] = srow[c];
    }
}

extern "C" void kernel_launch(void* const* d_in, const int* in_sizes, int n_in,
                              void* d_out, int out_size, void* d_ws, size_t ws_size,
                              hipStream_t stream) {
    const float* X  = (const float*)d_in[0];
    const float* W1 = (const float*)d_in[1];
    const float* b1 = (const float*)d_in[2];
    const float* W2 = (const float*)d_in[3];
    // d_in[4] (b2): constant shift, selection-invariant -> unused
    // d_in[5] (target_num_tokens): quota derived from out_size instead
    float* out = (float*)d_out;

    const int Hh = in_sizes[2];                 // 512
    const int H  = Hh * 2;                      // 1024
    const long long BN = (long long)in_sizes[0] / H;  // 147456 tokens
    const int B = 256;
    const int N = (int)(BN / B);                // 576
    const int n_seg = 32;                       // NUM_BRANCHES ** MAX_DEPTH
    const int seg_len = N / n_seg;              // 18
    const int rows_per_b = out_size / (B * H);  // 288
    const int quota = rows_per_b / n_seg;       // 9

    float* W1T    = (float*)d_ws;               // H*Hh floats = 2 MB
    float* scores = W1T + (size_t)H * Hh;       // BN floats

    dim3 tb(32, 8);
    dim3 tg(H / 32, Hh / 32);
    hipLaunchKernelGGL(transpose_w1_kernel, tg, tb, 0, stream, W1, W1T, Hh, H);

    dim3 gg((unsigned)(BN / TILE_BM));
    hipLaunchKernelGGL(score_kernel, gg, dim3(256), 0, stream, X, W1T, b1, W2, scores);

    dim3 sg(n_seg, B);
    hipLaunchKernelGGL(select_gather_kernel, sg, dim3(256), 0, stream,
                       X, scores, out, N, seg_len, quota, n_seg);
}

// Round 2
// 692.489 us; speedup vs baseline: 5.0658x; 5.0658x over previous
//
#include <hip/hip_runtime.h>
#include <math.h>

#define H_DIM 1024
#define HH_DIM 512

typedef _Float16 half8 __attribute__((ext_vector_type(8)));
typedef float f32x4 __attribute__((ext_vector_type(4)));

__device__ __forceinline__ void gload_lds16(const void* g, void* l) {
    __builtin_amdgcn_global_load_lds((const __attribute__((address_space(1))) uint32_t*)g,
                                     (__attribute__((address_space(3))) uint32_t*)l,
                                     16, 0, 0);
}

// ---- pack W1 [512][1024] fp32 -> two fp16 planes in MFMA-fragment order ----
// Bpack element offset: ((ks*2 + p)*32 + nfrag)*512 + lane*8 + j
// fragment content: lane holds B[k = ks*32 + (lane>>4)*8 + j][n = nfrag*16 + (lane&15)]
//                 = W1[n][k]  (k contiguous in W1 -> coalesced reads)
__global__ void pack_w1_kernel(const float* __restrict__ W1, _Float16* __restrict__ Bpack) {
    int tid  = blockIdx.x * 256 + threadIdx.x;   // 0..65535
    int lane = tid & 63;
    int nfg  = (tid >> 6) & 31;
    int ks   = tid >> 11;                        // 0..31
    int n    = nfg * 16 + (lane & 15);
    int k0   = ks * 32 + (lane >> 4) * 8;
    const float* src = W1 + (size_t)n * H_DIM + k0;
    float4 v0 = *(const float4*)src;
    float4 v1 = *(const float4*)(src + 4);
    float xs[8] = {v0.x, v0.y, v0.z, v0.w, v1.x, v1.y, v1.z, v1.w};
    half8 h0, h1;
#pragma unroll
    for (int j = 0; j < 8; ++j) {
        _Float16 a = (_Float16)xs[j];
        float r = xs[j] - (float)a;
        h0[j] = a;
        h1[j] = (_Float16)(r * 2048.0f);
    }
    size_t o0 = ((size_t)(ks * 2 + 0) * 32 + nfg) * 512 + lane * 8;
    size_t o1 = ((size_t)(ks * 2 + 1) * 32 + nfg) * 512 + lane * 8;
    *(half8*)(Bpack + o0) = h0;
    *(half8*)(Bpack + o1) = h1;
}

// ---- fused scorer GEMM1(+gelu+GEMM2 partial) via fp16-split MFMA ----
// block: 64 rows x 256 cols (nb = N-half), 4 waves each 64x64.
__global__ __launch_bounds__(256, 2)
void score_mfma_kernel(const float* __restrict__ X,
                       const _Float16* __restrict__ Bpack,
                       const float* __restrict__ b1,
                       const float* __restrict__ W2,
                       float* __restrict__ sparts, int tot_tokens) {
    __shared__ __align__(16) _Float16 As[2][4][64][8];    // 8 KB
    __shared__ __align__(16) _Float16 Bs[2][16][64][8];   // 32 KB
    __shared__ float red[4][64][16];                      // 16 KB

    const int t    = threadIdx.x;
    const int w    = t >> 6;
    const int lane = t & 63;
    const int nb   = blockIdx.y;                  // 0..1
    const size_t m0 = (size_t)blockIdx.x * 64;

    // A staging mapping: row = t>>2, k-quad = t&3 (8 consecutive k)
    const int ar    = t >> 2;
    const int ak    = (t & 3) * 8;
    const int aslot = (ar & 15) + ((t & 3) << 4); // lane slot within fragment
    const float* aptr = X + (m0 + ar) * H_DIM + ak;

    f32x4 acc1[4][4] = {};
    f32x4 acc2[4][4] = {};

    float4 av0 = *(const float4*)(aptr);
    float4 av1 = *(const float4*)(aptr + 4);

    for (int ks = 0; ks < 32; ++ks) {
        __syncthreads();  // previous iteration's fragment reads complete
        // convert A regs (this ks) -> two fp16 planes, write packed fragments
        {
            float xs[8] = {av0.x, av0.y, av0.z, av0.w, av1.x, av1.y, av1.z, av1.w};
            half8 h0, h1;
#pragma unroll
            for (int j = 0; j < 8; ++j) {
                _Float16 a = (_Float16)xs[j];
                float r = xs[j] - (float)a;
                h0[j] = a;
                h1[j] = (_Float16)(r * 2048.0f);
            }
            *(half8*)&As[0][ar >> 4][aslot][0] = h0;
            *(half8*)&As[1][ar >> 4][aslot][0] = h1;
        }
        // B async global->LDS (pre-packed, linear): 2 planes x 16 KB
        {
            const _Float16* bk = Bpack + ((size_t)(ks * 2) * 32 + (size_t)nb * 16) * 512;
            char* bs0 = (char*)&Bs[0][0][0][0];
            char* bs1 = (char*)&Bs[1][0][0][0];
#pragma unroll
            for (int r = 0; r < 4; ++r)
                gload_lds16(bk + (size_t)(r * 256 + t) * 8, bs0 + (size_t)(r * 256 + t) * 16);
#pragma unroll
            for (int r = 0; r < 4; ++r)
                gload_lds16(bk + 16384 + (size_t)(r * 256 + t) * 8, bs1 + (size_t)(r * 256 + t) * 16);
        }
        // prefetch A for next ks
        if (ks < 31) {
            av0 = *(const float4*)(aptr + (ks + 1) * 32);
            av1 = *(const float4*)(aptr + (ks + 1) * 32 + 4);
        }
        __syncthreads();  // drains vmcnt/lgkm: As + Bs ready

        half8 aA[4], aB[4], bA[4], bB[4];
#pragma unroll
        for (int mf = 0; mf < 4; ++mf) {
            aA[mf] = *(const half8*)&As[0][mf][lane][0];
            aB[mf] = *(const half8*)&As[1][mf][lane][0];
        }
#pragma unroll
        for (int nf = 0; nf < 4; ++nf) {
            bA[nf] = *(const half8*)&Bs[0][w * 4 + nf][lane][0];
            bB[nf] = *(const half8*)&Bs[1][w * 4 + nf][lane][0];
        }
#pragma unroll
        for (int mf = 0; mf < 4; ++mf)
#pragma unroll
            for (int nf = 0; nf < 4; ++nf)
                acc1[mf][nf] = __builtin_amdgcn_mfma_f32_16x16x32_f16(aA[mf], bA[nf], acc1[mf][nf], 0, 0, 0);
#pragma unroll
        for (int mf = 0; mf < 4; ++mf)
#pragma unroll
            for (int nf = 0; nf < 4; ++nf)
                acc2[mf][nf] = __builtin_amdgcn_mfma_f32_16x16x32_f16(aA[mf], bB[nf], acc2[mf][nf], 0, 0, 0);
#pragma unroll
        for (int mf = 0; mf < 4; ++mf)
#pragma unroll
            for (int nf = 0; nf < 4; ++nf)
                acc2[mf][nf] = __builtin_amdgcn_mfma_f32_16x16x32_f16(aB[mf], bA[nf], acc2[mf][nf], 0, 0, 0);
    }

    // epilogue: h = acc1 + acc2/2048 + b1 ; gelu ; * W2 ; reduce over cols
    const int hi = lane >> 4;        // 0..3
    const int lc = lane & 15;
    float b1v[4], w2v[4];
#pragma unroll
    for (int nf = 0; nf < 4; ++nf) {
        int c = nb * 256 + w * 64 + nf * 16 + lc;
        b1v[nf] = b1[c];
        w2v[nf] = W2[c];
    }
#pragma unroll
    for (int mf = 0; mf < 4; ++mf) {
#pragma unroll
        for (int i = 0; i < 4; ++i) {
            float s = 0.f;
#pragma unroll
            for (int nf = 0; nf < 4; ++nf) {
                float h = acc1[mf][nf][i] + acc2[mf][nf][i] * (1.0f / 2048.0f) + b1v[nf];
                float g = 0.5f * h * (1.0f + erff(h * 0.70710678118654752f));
                s = fmaf(g, w2v[nf], s);
            }
            red[w][mf * 16 + hi * 4 + i][lc] = s;
        }
    }
    __syncthreads();
    if (t < 64) {
        float s = 0.f;
#pragma unroll
        for (int ww = 0; ww < 4; ++ww)
#pragma unroll
            for (int c = 0; c < 16; ++c) s += red[ww][t][c];
        sparts[(size_t)nb * tot_tokens + m0 + t] = s;
    }
}

// ---- per-segment top-quota selection + gather (scores = sum of 2 partials) ----
__global__ void select_gather_kernel(const float* __restrict__ X,
                                     const float* __restrict__ sparts,
                                     float* __restrict__ out,
                                     int N, int seg_len, int quota, int n_seg,
                                     int tot_tokens) {
    const int seg = blockIdx.x;
    const int b   = blockIdx.y;
    __shared__ float sc[64];
    __shared__ int sel_idx[64];
    const int t = threadIdx.x;
    if (t < seg_len) {
        size_t tok = (size_t)b * N + (size_t)seg * seg_len + t;
        sc[t] = sparts[tok] + sparts[tok + tot_tokens];
    }
    __syncthreads();
    if (t == 0) {
        unsigned long long mask = 0ull;
        for (int it = 0; it < quota; ++it) {
            float best = 0.f;
            int bi = 0;
            bool found = false;
            for (int i = 0; i < seg_len; ++i) {
                if (!((mask >> i) & 1ull)) {
                    if (!found || sc[i] > best) { best = sc[i]; bi = i; found = true; }
                }
            }
            mask |= (1ull << bi);
        }
        int c = 0;
        for (int i = 0; i < seg_len; ++i)
            if ((mask >> i) & 1ull) sel_idx[c++] = i;  // ascending == sorted output
    }
    __syncthreads();
    const size_t HV = H_DIM / 4;
    const float4* xb = (const float4*)X + ((size_t)b * N + (size_t)seg * seg_len) * HV;
    float4* ob = (float4*)out + ((size_t)b * n_seg * quota + (size_t)seg * quota) * HV;
    for (int j = 0; j < quota; ++j) {
        const float4* srow = xb + (size_t)sel_idx[j] * HV;
        float4* drow = ob + (size_t)j * HV;
        for (int c = t; c < (int)HV; c += blockDim.x) drow[c] = srow[c];
    }
}

extern "C" void kernel_launch(void* const* d_in, const int* in_sizes, int n_in,
                              void* d_out, int out_size, void* d_ws, size_t ws_size,
                              hipStream_t stream) {
    const float* X  = (const float*)d_in[0];
    const float* W1 = (const float*)d_in[1];
    const float* b1 = (const float*)d_in[2];
    const float* W2 = (const float*)d_in[3];
    float* out = (float*)d_out;

    const int Hh = in_sizes[2];                        // 512
    const int H  = Hh * 2;                             // 1024
    const long long TOT = (long long)in_sizes[0] / H;  // 147456 tokens
    const int B = 256;
    const int N = (int)(TOT / B);                      // 576
    const int n_seg = 32;
    const int seg_len = N / n_seg;                     // 18
    const int rows_per_b = out_size / (B * H);         // 288
    const int quota = rows_per_b / n_seg;              // 9

    _Float16* Bpack = (_Float16*)d_ws;                           // 2 MB
    float* sparts   = (float*)((char*)d_ws + (size_t)2 * 1024 * 1024);  // 2*TOT floats

    hipLaunchKernelGGL(pack_w1_kernel, dim3(256), dim3(256), 0, stream, W1, Bpack);

    dim3 gg((unsigned)(TOT / 64), 2);
    hipLaunchKernelGGL(score_mfma_kernel, gg, dim3(256), 0, stream,
                       X, Bpack, b1, W2, sparts, (int)TOT);

    dim3 sg(n_seg, B);
    hipLaunchKernelGGL(select_gather_kernel, sg, dim3(256), 0, stream,
                       X, sparts, out, N, seg_len, quota, n_seg, (int)TOT);
}

// Round 3
// 691.627 us; speedup vs baseline: 5.0721x; 1.0012x over previous
//
#include <hip/hip_runtime.h>
#include <math.h>

#define H_DIM 1024
#define HH_DIM 512

typedef _Float16 half8 __attribute__((ext_vector_type(8)));
typedef float f32x4 __attribute__((ext_vector_type(4)));

__device__ __forceinline__ void gload_lds16(const void* g, void* l) {
    __builtin_amdgcn_global_load_lds((const __attribute__((address_space(1))) uint32_t*)g,
                                     (__attribute__((address_space(3))) uint32_t*)l,
                                     16, 0, 0);
}

// ---- pack W1 [512][1024] fp32 -> two fp16 planes in MFMA-fragment order ----
// Bpack element offset: ((ks*2 + p)*32 + nfrag)*512 + lane*8 + j
// lane holds B[k = ks*32 + (lane>>4)*8 + j][n = nfrag*16 + (lane&15)] = W1[n][k]
__global__ void pack_w1_kernel(const float* __restrict__ W1, _Float16* __restrict__ Bpack) {
    int tid  = blockIdx.x * 256 + threadIdx.x;   // 0..65535
    int lane = tid & 63;
    int nfg  = (tid >> 6) & 31;
    int ks   = tid >> 11;                        // 0..31
    int n    = nfg * 16 + (lane & 15);
    int k0   = ks * 32 + (lane >> 4) * 8;
    const float* src = W1 + (size_t)n * H_DIM + k0;
    float4 v0 = *(const float4*)src;
    float4 v1 = *(const float4*)(src + 4);
    float xs[8] = {v0.x, v0.y, v0.z, v0.w, v1.x, v1.y, v1.z, v1.w};
    half8 h0, h1;
#pragma unroll
    for (int j = 0; j < 8; ++j) {
        _Float16 a = (_Float16)xs[j];
        float r = xs[j] - (float)a;
        h0[j] = a;
        h1[j] = (_Float16)(r * 2048.0f);
    }
    size_t o0 = ((size_t)(ks * 2 + 0) * 32 + nfg) * 512 + lane * 8;
    size_t o1 = ((size_t)(ks * 2 + 1) * 32 + nfg) * 512 + lane * 8;
    *(half8*)(Bpack + o0) = h0;
    *(half8*)(Bpack + o1) = h1;
}

// ---- fused scorer via fp16-split MFMA, double-buffered 2-phase pipeline ----
// block: 64 rows x 256 cols (nb half of N), 4 waves each 64x64.
// LDS map (80 KB total, red overlaid):
//   As: [buf][plane][mf][slot64][8]h  bytes [0, 16384)      off=((buf*2+p)*4+mf)*1024+slot*16
//   Bs: [buf][plane][nf16][slot64][8]h bytes 16384+buf*32768+(p*16+nf)*1024+slot*16
//   red: float[4][64][17] at base (epilogue only, after barrier)
__global__ __launch_bounds__(256, 2)
void score_mfma_kernel(const float* __restrict__ X,
                       const _Float16* __restrict__ Bpack,
                       const float* __restrict__ b1,
                       const float* __restrict__ W2,
                       float* __restrict__ sparts, int tot_tokens) {
    __shared__ __align__(16) char smem[81920];

    const int t    = threadIdx.x;
    const int w    = t >> 6;
    const int lane = t & 63;
    const int nb   = blockIdx.y;
    const size_t m0 = (size_t)blockIdx.x * 64;

    // A staging: thread t handles row w*16+(t&15), k-quad (t>>4)&3; write slot = t&63 (linear)
    const int arow  = w * 16 + (t & 15);
    const int aq    = (t >> 4) & 3;
    const int aslot = t & 63;
    const float* aptr = X + (m0 + arow) * H_DIM + aq * 8;

    f32x4 acc1[4][4] = {};
    f32x4 acc2[4][4] = {};

#define CONVERT_WRITE(buf)                                                          \
    do {                                                                            \
        float xs[8] = {av0.x, av0.y, av0.z, av0.w, av1.x, av1.y, av1.z, av1.w};     \
        half8 h0, h1;                                                               \
        _Pragma("unroll") for (int j = 0; j < 8; ++j) {                             \
            _Float16 a = (_Float16)xs[j];                                           \
            float r = xs[j] - (float)a;                                             \
            h0[j] = a;                                                              \
            h1[j] = (_Float16)(r * 2048.0f);                                        \
        }                                                                           \
        *(half8*)(smem + (((buf) * 2 + 0) * 4 + w) * 1024 + aslot * 16) = h0;       \
        *(half8*)(smem + (((buf) * 2 + 1) * 4 + w) * 1024 + aslot * 16) = h1;       \
    } while (0)

#define STAGE_B(ks, buf)                                                            \
    do {                                                                            \
        const _Float16* bk0 = Bpack + ((size_t)((ks) * 2) * 32 + (size_t)nb * 16) * 512; \
        char* bdst = smem + 16384 + (buf) * 32768;                                  \
        _Pragma("unroll") for (int r = 0; r < 8; ++r) {                             \
            int idx = r * 256 + t;                                                  \
            gload_lds16(bk0 + (idx >> 10) * 16384 + (idx & 1023) * 8,               \
                        bdst + idx * 16);                                           \
        }                                                                           \
    } while (0)

    // ---- prologue: fill buffer 0, prefetch A(1) regs ----
    float4 av0 = *(const float4*)(aptr);
    float4 av1 = *(const float4*)(aptr + 4);
    CONVERT_WRITE(0);
    STAGE_B(0, 0);
    __builtin_amdgcn_sched_barrier(0);
    av0 = *(const float4*)(aptr + 32);
    av1 = *(const float4*)(aptr + 36);
    __builtin_amdgcn_sched_barrier(0);
    asm volatile("s_waitcnt vmcnt(2) lgkmcnt(0)" ::: "memory");
    __builtin_amdgcn_sched_barrier(0);
    __builtin_amdgcn_s_barrier();

    int cur = 0;
    for (int ks = 0; ks < 32; ++ks) {
        const int nxt = cur ^ 1;
        if (ks < 31) {
            // issue next tile: 8 B-loads (async -> LDS), A convert+write, A(ks+2) prefetch
            STAGE_B(ks + 1, nxt);
            __builtin_amdgcn_sched_barrier(0);
            CONVERT_WRITE(nxt);  // av holds A(ks+1)
            if (ks < 30) {
                av0 = *(const float4*)(aptr + (ks + 2) * 32);
                av1 = *(const float4*)(aptr + (ks + 2) * 32 + 4);
            }
            __builtin_amdgcn_sched_barrier(0);
        }

        // fragment reads from cur (compiler inserts precise lgkm waits)
        half8 aA[4], aB[4], bA[4], bB[4];
#pragma unroll
        for (int mf = 0; mf < 4; ++mf) {
            aA[mf] = *(const half8*)(smem + ((cur * 2 + 0) * 4 + mf) * 1024 + lane * 16);
            aB[mf] = *(const half8*)(smem + ((cur * 2 + 1) * 4 + mf) * 1024 + lane * 16);
        }
#pragma unroll
        for (int nf = 0; nf < 4; ++nf) {
            bA[nf] = *(const half8*)(smem + 16384 + cur * 32768 + (w * 4 + nf) * 1024 + lane * 16);
            bB[nf] = *(const half8*)(smem + 16384 + cur * 32768 + (16 + w * 4 + nf) * 1024 + lane * 16);
        }

#pragma unroll
        for (int mf = 0; mf < 4; ++mf)
#pragma unroll
            for (int nf = 0; nf < 4; ++nf)
                acc1[mf][nf] = __builtin_amdgcn_mfma_f32_16x16x32_f16(aA[mf], bA[nf], acc1[mf][nf], 0, 0, 0);
#pragma unroll
        for (int mf = 0; mf < 4; ++mf)
#pragma unroll
            for (int nf = 0; nf < 4; ++nf)
                acc2[mf][nf] = __builtin_amdgcn_mfma_f32_16x16x32_f16(aA[mf], bB[nf], acc2[mf][nf], 0, 0, 0);
#pragma unroll
        for (int mf = 0; mf < 4; ++mf)
#pragma unroll
            for (int nf = 0; nf < 4; ++nf)
                acc2[mf][nf] = __builtin_amdgcn_mfma_f32_16x16x32_f16(aB[mf], bA[nf], acc2[mf][nf], 0, 0, 0);

        if (ks < 31) {
            // drain only the 8 B-loads of the next tile (A prefetch stays in flight),
            // plus own LDS ops (frag reads + As writes) before the barrier.
            if (ks < 30) {
                asm volatile("s_waitcnt vmcnt(2) lgkmcnt(0)" ::: "memory");
            } else {
                asm volatile("s_waitcnt vmcnt(0) lgkmcnt(0)" ::: "memory");
            }
            __builtin_amdgcn_sched_barrier(0);
            __builtin_amdgcn_s_barrier();
        }
        cur = nxt;
    }

    // ---- epilogue: h = acc1 + acc2/2048 + b1; gelu; *W2; reduce over 512 cols ----
    __syncthreads();  // all tile reads done before red overlays As/Bs space
    float* red = (float*)smem;  // [4][64][17]
    const int hi = lane >> 4;
    const int lc = lane & 15;
    float b1v[4], w2v[4];
#pragma unroll
    for (int nf = 0; nf < 4; ++nf) {
        int c = nb * 256 + w * 64 + nf * 16 + lc;
        b1v[nf] = b1[c];
        w2v[nf] = W2[c];
    }
#pragma unroll
    for (int mf = 0; mf < 4; ++mf) {
#pragma unroll
        for (int i = 0; i < 4; ++i) {
            float s = 0.f;
#pragma unroll
            for (int nf = 0; nf < 4; ++nf) {
                float h = acc1[mf][nf][i] + acc2[mf][nf][i] * (1.0f / 2048.0f) + b1v[nf];
                float g = 0.5f * h * (1.0f + erff(h * 0.70710678118654752f));
                s = fmaf(g, w2v[nf], s);
            }
            red[(w * 64 + mf * 16 + hi * 4 + i) * 17 + lc] = s;
        }
    }
    __syncthreads();
    if (t < 64) {
        float s = 0.f;
#pragma unroll
        for (int ww = 0; ww < 4; ++ww)
#pragma unroll
            for (int c = 0; c < 16; ++c) s += red[(ww * 64 + t) * 17 + c];
        sparts[(size_t)nb * tot_tokens + m0 + t] = s;
    }
}

// ---- per-segment top-quota selection + gather (scores = sum of 2 partials) ----
__global__ void select_gather_kernel(const float* __restrict__ X,
                                     const float* __restrict__ sparts,
                                     float* __restrict__ out,
                                     int N, int seg_len, int quota, int n_seg,
                                     int tot_tokens) {
    const int seg = blockIdx.x;
    const int b   = blockIdx.y;
    __shared__ float sc[64];
    __shared__ int sel_idx[64];
    const int t = threadIdx.x;
    if (t < seg_len) {
        size_t tok = (size_t)b * N + (size_t)seg * seg_len + t;
        sc[t] = sparts[tok] + sparts[tok + tot_tokens];
    }
    __syncthreads();
    if (t == 0) {
        unsigned long long mask = 0ull;
        for (int it = 0; it < quota; ++it) {
            float best = 0.f;
            int bi = 0;
            bool found = false;
            for (int i = 0; i < seg_len; ++i) {
                if (!((mask >> i) & 1ull)) {
                    if (!found || sc[i] > best) { best = sc[i]; bi = i; found = true; }
                }
            }
            mask |= (1ull << bi);
        }
        int c = 0;
        for (int i = 0; i < seg_len; ++i)
            if ((mask >> i) & 1ull) sel_idx[c++] = i;  // ascending == sorted output
    }
    __syncthreads();
    const size_t HV = H_DIM / 4;
    const float4* xb = (const float4*)X + ((size_t)b * N + (size_t)seg * seg_len) * HV;
    float4* ob = (float4*)out + ((size_t)b * n_seg * quota + (size_t)seg * quota) * HV;
    for (int j = 0; j < quota; ++j) {
        const float4* srow = xb + (size_t)sel_idx[j] * HV;
        float4* drow = ob + (size_t)j * HV;
        for (int c = t; c < (int)HV; c += blockDim.x) drow[c] = srow[c];
    }
}

extern "C" void kernel_launch(void* const* d_in, const int* in_sizes, int n_in,
                              void* d_out, int out_size, void* d_ws, size_t ws_size,
                              hipStream_t stream) {
    const float* X  = (const float*)d_in[0];
    const float* W1 = (const float*)d_in[1];
    const float* b1 = (const float*)d_in[2];
    const float* W2 = (const float*)d_in[3];
    float* out = (float*)d_out;

    const int Hh = in_sizes[2];                        // 512
    const int H  = Hh * 2;                             // 1024
    const long long TOT = (long long)in_sizes[0] / H;  // 147456 tokens
    const int B = 256;
    const int N = (int)(TOT / B);                      // 576
    const int n_seg = 32;
    const int seg_len = N / n_seg;                     // 18
    const int rows_per_b = out_size / (B * H);         // 288
    const int quota = rows_per_b / n_seg;              // 9

    _Float16* Bpack = (_Float16*)d_ws;                                  // 2 MB
    float* sparts   = (float*)((char*)d_ws + (size_t)2 * 1024 * 1024);  // 2*TOT floats

    hipLaunchKernelGGL(pack_w1_kernel, dim3(256), dim3(256), 0, stream, W1, Bpack);

    dim3 gg((unsigned)(TOT / 64), 2);
    hipLaunchKernelGGL(score_mfma_kernel, gg, dim3(256), 0, stream,
                       X, Bpack, b1, W2, sparts, (int)TOT);

    dim3 sg(n_seg, B);
    hipLaunchKernelGGL(select_gather_kernel, sg, dim3(256), 0, stream,
                       X, sparts, out, N, seg_len, quota, n_seg, (int)TOT);
}